// Round 1
// baseline (124.557 us; speedup 1.0000x reference)
//
#include <hip/hip_runtime.h>
#include <math.h>

#define B_    16
#define N_    128
#define F_IN_ 8
#define S_    8
#define F_OUT_ 64
#define KN_HID_ 32
#define FC_HID_ 32

// workspace layout (float offsets)
//  w2x  : [B*N][KN_HID][F_OUT] = 2048*32*64 = 4194304
//  b2x  : [B*N][F_OUT]         = 131072
//  xroot: [B*N][F_OUT]         = 131072
//  pool : [B][F_OUT]           = 1024
#define W2X_OFF   0
#define B2X_OFF   4194304
#define XROOT_OFF (B2X_OFF + 131072)
#define POOL_OFF  (XROOT_OFF + 131072)

// ---------------------------------------------------------------------------
// k1: per source node (b,i) precompute
//   W2x[k,o]  = sum_f X[b,i,f] * kn_w2[k, f*64+o]
//   b2x[o]    = sum_f X[b,i,f] * kn_b2[f*64+o]
//   xroot[o]  = sum_f X[b,i,f] * root_w[f,o]
// block 0 additionally zeroes the pooled accumulator.
// ---------------------------------------------------------------------------
__global__ __launch_bounds__(256) void k1_precompute(
    const float* __restrict__ X, const float* __restrict__ kn_w2,
    const float* __restrict__ kn_b2, const float* __restrict__ root_w,
    float* __restrict__ ws)
{
    const int bi = blockIdx.x;          // b*N + i
    const int t  = threadIdx.x;

    float x[F_IN_];
#pragma unroll
    for (int f = 0; f < F_IN_; ++f) x[f] = X[bi * F_IN_ + f];

    const int o     = t & 63;
    const int kbase = t >> 6;           // 0..3
    float* w2x = ws + W2X_OFF + (size_t)bi * (KN_HID_ * F_OUT_);
#pragma unroll
    for (int j = 0; j < 8; ++j) {
        const int k = kbase + 4 * j;    // covers 0..31
        float acc = 0.f;
#pragma unroll
        for (int f = 0; f < F_IN_; ++f)
            acc += x[f] * kn_w2[k * (F_IN_ * F_OUT_) + f * F_OUT_ + o];
        w2x[k * F_OUT_ + o] = acc;
    }

    if (t < F_OUT_) {
        float accb = 0.f, accr = 0.f;
#pragma unroll
        for (int f = 0; f < F_IN_; ++f) {
            accb += x[f] * kn_b2[f * F_OUT_ + t];
            accr += x[f] * root_w[f * F_OUT_ + t];
        }
        ws[B2X_OFF + bi * F_OUT_ + t]   = accb;
        ws[XROOT_OFF + bi * F_OUT_ + t] = accr;
    }

    if (blockIdx.x == 0) {
        for (int p = t; p < B_ * F_OUT_; p += 256) ws[POOL_OFF + p] = 0.f;
    }
}

// ---------------------------------------------------------------------------
// k2: one 64-thread block (1 wave) per destination node (b,n). lane = o.
//   acc[o] = sum_{i: A!=0} A * ( sum_k h[b,n,i,k]*W2x[b,i,k,o] + b2x[b,i,o] )
//   acc += xroot + conv_b; relu; atomicAdd into pool[b,o]
// ---------------------------------------------------------------------------
__global__ __launch_bounds__(64) void k2_edges(
    const float* __restrict__ A, const float* __restrict__ E,
    const float* __restrict__ kn_w1, const float* __restrict__ kn_b1,
    const float* __restrict__ conv_b, float* __restrict__ ws)
{
    const int bn = blockIdx.x;          // b*N + n
    const int b  = bn >> 7;
    const int o  = threadIdx.x;         // 0..63

    __shared__ float a_row[N_];
    __shared__ float h[KN_HID_];

    a_row[o]      = A[(size_t)bn * N_ + o];
    a_row[o + 64] = A[(size_t)bn * N_ + o + 64];
    __syncthreads();

    float acc = 0.f;
    const float* w2x_b = ws + W2X_OFF + (size_t)b * (N_ * KN_HID_ * F_OUT_);
    const float* b2x_b = ws + B2X_OFF + (size_t)b * (N_ * F_OUT_);

    for (int i = 0; i < N_; ++i) {
        const float a = a_row[i];       // wave-uniform
        if (a == 0.f) continue;

        if (o < KN_HID_) {
            const float* e = E + ((size_t)bn * N_ + i) * S_;
            float v = kn_b1[o];
#pragma unroll
            for (int s = 0; s < S_; ++s)
                v += e[s] * kn_w1[s * KN_HID_ + o];
            h[o] = v > 0.f ? v : 0.f;
        }
        __syncthreads();

        const float* w = w2x_b + (size_t)i * (KN_HID_ * F_OUT_) + o;
        float edge = b2x_b[i * F_OUT_ + o];
#pragma unroll
        for (int k = 0; k < KN_HID_; ++k)
            edge += h[k] * w[k * F_OUT_];
        acc += a * edge;
        __syncthreads();                // protect h before next overwrite
    }

    acc += ws[XROOT_OFF + (size_t)bn * F_OUT_ + o] + conv_b[o];
    acc = acc > 0.f ? acc : 0.f;
    atomicAdd(&ws[POOL_OFF + b * F_OUT_ + o], acc);
}

// ---------------------------------------------------------------------------
// k3: head. One block per batch element.
//   p = pool[b,:]/N; y = relu(p@fc_w+fc_b); out = sigmoid(y@out_w+out_b)
// ---------------------------------------------------------------------------
__global__ __launch_bounds__(64) void k3_head(
    const float* __restrict__ fc_w, const float* __restrict__ fc_b,
    const float* __restrict__ out_w, const float* __restrict__ out_b,
    const float* __restrict__ pool, float* __restrict__ out)
{
    const int b = blockIdx.x;
    const int t = threadIdx.x;
    __shared__ float p[F_OUT_];
    __shared__ float y[FC_HID_];

    p[t] = pool[b * F_OUT_ + t] * (1.0f / (float)N_);
    __syncthreads();

    if (t < FC_HID_) {
        float v = fc_b[t];
#pragma unroll
        for (int o = 0; o < F_OUT_; ++o) v += p[o] * fc_w[o * FC_HID_ + t];
        y[t] = v > 0.f ? v : 0.f;
    }
    __syncthreads();

    if (t == 0) {
        float z = out_b[0];
#pragma unroll
        for (int j = 0; j < FC_HID_; ++j) z += y[j] * out_w[j];
        out[b] = 1.f / (1.f + expf(-z));
    }
}

extern "C" void kernel_launch(void* const* d_in, const int* in_sizes, int n_in,
                              void* d_out, int out_size, void* d_ws, size_t ws_size,
                              hipStream_t stream)
{
    const float* A      = (const float*)d_in[0];
    const float* X      = (const float*)d_in[1];
    const float* E      = (const float*)d_in[2];
    const float* kn_w1  = (const float*)d_in[3];
    const float* kn_b1  = (const float*)d_in[4];
    const float* kn_w2  = (const float*)d_in[5];
    const float* kn_b2  = (const float*)d_in[6];
    const float* root_w = (const float*)d_in[7];
    const float* conv_b = (const float*)d_in[8];
    const float* fc_w   = (const float*)d_in[9];
    const float* fc_b   = (const float*)d_in[10];
    const float* out_w  = (const float*)d_in[11];
    const float* out_b  = (const float*)d_in[12];

    float* ws  = (float*)d_ws;
    float* out = (float*)d_out;

    k1_precompute<<<B_ * N_, 256, 0, stream>>>(X, kn_w2, kn_b2, root_w, ws);
    k2_edges<<<B_ * N_, 64, 0, stream>>>(A, E, kn_w1, kn_b1, conv_b, ws);
    k3_head<<<B_, 64, 0, stream>>>(fc_w, fc_b, out_w, out_b, ws + POOL_OFF, out);
}